// Round 3
// baseline (5975.366 us; speedup 1.0000x reference)
//
#include <hip/hip_runtime.h>
#include <hip/hip_bf16.h>
#include <cstdint>
#include <cstddef>

typedef _Float16 half8 __attribute__((ext_vector_type(8)));
typedef _Float16 half4 __attribute__((ext_vector_type(4)));
typedef float floatx4 __attribute__((ext_vector_type(4)));

#define B_ 256
#define T_ 168
#define H_ 1024
#define WS_ 64
#define LAG_ 168
#define LAT_ 128

// ---------------- fp32 -> fp16 conversion (vectorized x4) ----------------
__global__ void cvt_f32_f16_v4(const float4* __restrict__ src, half4* __restrict__ dst, int n4) {
    int i = blockIdx.x * blockDim.x + threadIdx.x;
    if (i < n4) {
        float4 v = src[i];
        half4 o;
        o[0] = (_Float16)v.x; o[1] = (_Float16)v.y;
        o[2] = (_Float16)v.z; o[3] = (_Float16)v.w;
        dst[i] = o;
    }
}

// ---------------- encoder layers 1,2: leaky(in @ W^T + b) ----------------
__global__ void enc12(const float* __restrict__ in, const float* __restrict__ W,
                      const float* __restrict__ bias, float* __restrict__ outb, int infeat) {
    int r = blockIdx.x, j = threadIdx.x;
    const float* row = in + (size_t)r * infeat;
    const float* w   = W  + (size_t)j * infeat;
    float s = bias[j];
    for (int k = 0; k < infeat; ++k) s += row[k] * w[k];
    outb[(size_t)r * blockDim.x + j] = (s >= 0.f) ? s : 0.01f * s;
}

// ---------------- encoder layer 3: h0 = h2 @ W3^T + b3 ----------------
__global__ void enc3(const float* __restrict__ h2, const float* __restrict__ W3,
                     const float* __restrict__ b3, float* __restrict__ hprev32,
                     _Float16* __restrict__ h0f16) {
    __shared__ float s[LAT_];
    int r = blockIdx.x;
    if (threadIdx.x < LAT_) s[threadIdx.x] = h2[(size_t)r * LAT_ + threadIdx.x];
    __syncthreads();
    for (int j = threadIdx.x; j < H_; j += 256) {
        const float* w = W3 + (size_t)j * LAT_;
        float acc = b3[j];
        #pragma unroll 8
        for (int k = 0; k < LAT_; ++k) acc += s[k] * w[k];
        hprev32[(size_t)r * H_ + j] = acc;
        h0f16[(size_t)r * H_ + j]   = (_Float16)acc;
    }
}

// ---------------- persistent GRU: all 168 steps in one launch ----------------
// grid 256 WGs (plain launch; co-residency by capacity: LDS 62.7KB -> >=2 WG/CU,
// VGPR<=512 -> >=1 block/CU, grid == #CUs). pi = blockIdx&15 -> rows [16pi,+16);
// qi = blockIdx>>4 -> units [64qi,+64). 4 waves; wave w owns units [64qi+16w,+16)
// x 3 gates. Whh fragments resident in VGPRs (384/wave), h carried in registers.
// Cross-WG sync: per-pi 16-WG sense barrier with agent fences (wbl2/inv).
__global__ __launch_bounds__(256, 1) void gru_persistent(
    _Float16* __restrict__ hb0, _Float16* __restrict__ hb1,
    const float* __restrict__ hprev32, const _Float16* __restrict__ whh16,
    const _Float16* __restrict__ wih16, const _Float16* __restrict__ x16,
    const float* __restrict__ bih, const float* __restrict__ bhh,
    const float* __restrict__ Wo, float* __restrict__ partials,
    unsigned* __restrict__ bar)
{
    __shared__ __align__(16) _Float16 Ash[16 * 1032];   // 16 h-rows x 1024k (+8 pad)
    __shared__ __align__(16) _Float16 Wsh[192 * 72];    // Wih slice: 192 gate-cols x 64k (+8 pad)
    __shared__ __align__(16) _Float16 Hsh[1024];        // h-out transpose: 16 rows x 64 units

    const int tid  = threadIdx.x;
    const int w    = tid >> 6;
    const int lane = tid & 63;
    const int m16  = lane & 15;
    const int quad = lane >> 4;
    const int pi   = blockIdx.x & 15;
    const int qi   = blockIdx.x >> 4;
    const int pi16 = pi << 4;
    const int u    = (qi << 6) + (w << 4) + m16;   // this lane's hidden unit

    // Wih slice -> LDS (once)
    for (int idx = tid; idx < 1536; idx += 256) {
        int rowl = idx >> 3, ch = idx & 7;
        int g = rowl >> 6, ru = rowl & 63;
        *(uint4*)(&Wsh[rowl * 72 + (ch << 3)]) =
            *(const uint4*)(wih16 + (size_t)(((g << 10) + (qi << 6) + ru) << 6) + (ch << 3));
    }

    // Whh fragments -> VGPRs (once). B-frag layout: col=lane&15 -> unit, k=quad*8+j.
    half8 barr[3][32];
    #pragma unroll
    for (int g = 0; g < 3; ++g) {
        const _Float16* bp = whh16 + ((size_t)((g << 10) + u) << 10) + (quad << 3);
        #pragma unroll
        for (int c = 0; c < 32; ++c) barr[g][c] = *(const half8*)(bp + (c << 5));
    }

    const float b_r  = bih[u]          + bhh[u];
    const float b_z  = bih[H_ + u]     + bhh[H_ + u];
    const float b_in = bih[2 * H_ + u];             // b_hn must stay separate (n-gate)
    const float b_hn = bhh[2 * H_ + u];
    const float wo_u = Wo[u];

    float hreg[4];
    #pragma unroll
    for (int i = 0; i < 4; ++i)
        hreg[i] = hprev32[((size_t)(pi16 + (quad << 2) + i) << 10) + u];

    __syncthreads();

    unsigned* cnt = bar + pi * 32;
    unsigned* gen = bar + 512 + pi * 32;

    for (int t = 0; t < T_; ++t) {
        const _Float16* hsrc = (t & 1) ? hb1 : hb0;
        _Float16*       hdst = (t & 1) ? hb0 : hb1;

        // stage this pi-block's h rows (16 x 1024 fp16 = 32 KB) -> LDS
        #pragma unroll
        for (int it = 0; it < 8; ++it) {
            int c = tid + (it << 8);
            int row = c >> 7, koff = (c & 127) << 3;
            *(uint4*)(&Ash[row * 1032 + koff]) =
                *(const uint4*)(hsrc + ((size_t)(pi16 + row) << 10) + koff);
        }
        __syncthreads();

        floatx4 acc_r  = {b_r,  b_r,  b_r,  b_r };
        floatx4 acc_z  = {b_z,  b_z,  b_z,  b_z };
        floatx4 acc_in = {b_in, b_in, b_in, b_in};
        floatx4 acc_hn = {b_hn, b_hn, b_hn, b_hn};

        // gi = x_t @ Wih^T  (K=64, Wih from LDS)
        #pragma unroll
        for (int c = 0; c < 2; ++c) {
            half8 ax = *(const half8*)(x16 + (((size_t)t << 8) + pi16 + m16) * WS_ + (c << 5) + (quad << 3));
            half8 p0 = *(const half8*)(&Wsh[((w << 4) + m16) * 72        + (c << 5) + (quad << 3)]);
            half8 p1 = *(const half8*)(&Wsh[(64 + (w << 4) + m16) * 72   + (c << 5) + (quad << 3)]);
            half8 p2 = *(const half8*)(&Wsh[(128 + (w << 4) + m16) * 72  + (c << 5) + (quad << 3)]);
            acc_r  = __builtin_amdgcn_mfma_f32_16x16x32_f16(ax, p0, acc_r,  0, 0, 0);
            acc_z  = __builtin_amdgcn_mfma_f32_16x16x32_f16(ax, p1, acc_z,  0, 0, 0);
            acc_in = __builtin_amdgcn_mfma_f32_16x16x32_f16(ax, p2, acc_in, 0, 0, 0);
        }

        // gh = h @ Whh^T  (K=1024, B resident in VGPRs)
        #pragma unroll
        for (int c = 0; c < 32; ++c) {
            half8 a = *(const half8*)(&Ash[m16 * 1032 + (c << 5) + (quad << 3)]);
            acc_r  = __builtin_amdgcn_mfma_f32_16x16x32_f16(a, barr[0][c], acc_r,  0, 0, 0);
            acc_z  = __builtin_amdgcn_mfma_f32_16x16x32_f16(a, barr[1][c], acc_z,  0, 0, 0);
            acc_hn = __builtin_amdgcn_mfma_f32_16x16x32_f16(a, barr[2][c], acc_hn, 0, 0, 0);
        }

        // GRU nonlinearity; h stays in registers
        float pv[4];
        #pragma unroll
        for (int i = 0; i < 4; ++i) {
            float rg = 1.f / (1.f + __expf(-acc_r[i]));
            float zg = 1.f / (1.f + __expf(-acc_z[i]));
            float ng = tanhf(acc_in[i] + rg * acc_hn[i]);
            float hn2 = (1.f - zg) * ng + zg * hreg[i];
            hreg[i] = hn2;
            pv[i] = hn2 * wo_u;
            Hsh[((quad << 2) + i) * 64 + (w << 4) + m16] = (_Float16)hn2;
        }
        #pragma unroll
        for (int m = 1; m < 16; m <<= 1) {
            #pragma unroll
            for (int i = 0; i < 4; ++i) pv[i] += __shfl_xor(pv[i], m);
        }
        if (m16 == 0) {
            #pragma unroll
            for (int i = 0; i < 4; ++i)
                partials[((size_t)t * B_ + pi16 + (quad << 2) + i) * 64 + (qi << 2) + w] = pv[i];
        }
        __syncthreads();

        // contiguous h16 write-back (8 B / thread)
        {
            uint2 hv = *(const uint2*)(&Hsh[tid << 2]);
            *(uint2*)(hdst + ((size_t)(pi16 + (tid >> 4)) << 10) + (qi << 6) + ((tid & 15) << 2)) = hv;
        }

        if (t < T_ - 1) {
            __builtin_amdgcn_fence(__ATOMIC_RELEASE, "agent");   // waitcnt + wbl2 (each wave)
            __syncthreads();
            if (tid == 0) {
                unsigned old = __hip_atomic_fetch_add(cnt, 1u, __ATOMIC_ACQ_REL, __HIP_MEMORY_SCOPE_AGENT);
                if (old == 15u) {
                    __hip_atomic_store(cnt, 0u, __ATOMIC_RELAXED, __HIP_MEMORY_SCOPE_AGENT);
                    __hip_atomic_store(gen, (unsigned)(t + 1), __ATOMIC_RELEASE, __HIP_MEMORY_SCOPE_AGENT);
                } else {
                    while (__hip_atomic_load(gen, __ATOMIC_ACQUIRE, __HIP_MEMORY_SCOPE_AGENT) < (unsigned)(t + 1))
                        __builtin_amdgcn_s_sleep(2);
                }
            }
            __syncthreads();
            __builtin_amdgcn_fence(__ATOMIC_ACQUIRE, "agent");   // buffer_inv: drop stale L1/L2
        }
    }
}

// ---------------- final: out[r,t] = sum_q partials[t,r,q] + bo ----------------
__global__ void out_reduce(const float* __restrict__ partials, const float* __restrict__ bo,
                           float* __restrict__ out) {
    int t = blockIdx.x, r = threadIdx.x;
    const float* p = partials + ((size_t)t * B_ + r) * 64;
    float s = 0.f;
    #pragma unroll
    for (int i = 0; i < 64; ++i) s += p[i];
    out[(size_t)r * T_ + t] = s + bo[0];
}

extern "C" void kernel_launch(void* const* d_in, const int* in_sizes, int n_in,
                              void* d_out, int out_size, void* d_ws, size_t ws_size,
                              hipStream_t stream) {
    const float* lag  = (const float*)d_in[0];
    const float* curr = (const float*)d_in[1];
    const float* W1   = (const float*)d_in[2];
    const float* b1   = (const float*)d_in[3];
    const float* W2   = (const float*)d_in[4];
    const float* b2   = (const float*)d_in[5];
    const float* W3   = (const float*)d_in[6];
    const float* b3   = (const float*)d_in[7];
    const float* Wih  = (const float*)d_in[8];
    const float* Whh  = (const float*)d_in[9];
    const float* bih  = (const float*)d_in[10];
    const float* bhh  = (const float*)d_in[11];
    const float* Wo   = (const float*)d_in[12];
    const float* bo   = (const float*)d_in[13];
    float* out = (float*)d_out;

    char* ws = (char*)d_ws;
    size_t off = 0;
    auto alloc = [&](size_t bytes) -> void* {
        void* p = ws + off;
        off += (bytes + 255) & ~(size_t)255;
        return p;
    };
    _Float16* whh16 = (_Float16*)alloc((size_t)3 * H_ * H_ * 2);
    _Float16* wih16 = (_Float16*)alloc((size_t)3 * H_ * WS_ * 2);
    _Float16* x16   = (_Float16*)alloc((size_t)T_ * B_ * WS_ * 2);
    _Float16* hb0   = (_Float16*)alloc((size_t)B_ * H_ * 2);
    _Float16* hb1   = (_Float16*)alloc((size_t)B_ * H_ * 2);
    float* hprev32  = (float*)alloc((size_t)B_ * H_ * 4);
    float* h1       = (float*)alloc((size_t)B_ * 64 * 4);
    float* h2       = (float*)alloc((size_t)B_ * LAT_ * 4);
    float* partials = (float*)alloc((size_t)T_ * B_ * 64 * 4);
    unsigned* bar   = (unsigned*)alloc(1024 * 4);

    hipMemsetAsync(bar, 0, 1024 * 4, stream);

    int n4;
    n4 = 3 * H_ * H_ / 4;
    cvt_f32_f16_v4<<<(n4 + 255) / 256, 256, 0, stream>>>((const float4*)Whh, (half4*)whh16, n4);
    n4 = 3 * H_ * WS_ / 4;
    cvt_f32_f16_v4<<<(n4 + 255) / 256, 256, 0, stream>>>((const float4*)Wih, (half4*)wih16, n4);
    n4 = T_ * B_ * WS_ / 4;
    cvt_f32_f16_v4<<<(n4 + 255) / 256, 256, 0, stream>>>((const float4*)curr, (half4*)x16, n4);

    enc12<<<B_, 64, 0, stream>>>(lag, W1, b1, h1, LAG_);
    enc12<<<B_, LAT_, 0, stream>>>(h1, W2, b2, h2, 64);
    enc3<<<B_, 256, 0, stream>>>(h2, W3, b3, hprev32, hb0);

    gru_persistent<<<dim3(256), dim3(256), 0, stream>>>(
        hb0, hb1, hprev32, whh16, wih16, x16, bih, bhh, Wo, partials, bar);

    out_reduce<<<T_, B_, 0, stream>>>(partials, bo, out);
}

// Round 4
// 1456.600 us; speedup vs baseline: 4.1023x; 4.1023x over previous
//
#include <hip/hip_runtime.h>
#include <hip/hip_bf16.h>
#include <cstdint>
#include <cstddef>

typedef _Float16 half8 __attribute__((ext_vector_type(8)));
typedef _Float16 half4 __attribute__((ext_vector_type(4)));
typedef float floatx4 __attribute__((ext_vector_type(4)));

#define B_ 256
#define T_ 168
#define H_ 1024
#define WS_ 64
#define LAG_ 168
#define LAT_ 128

// ---------------- fp32 -> fp16 conversion (vectorized x4) ----------------
__global__ void cvt_f32_f16_v4(const float4* __restrict__ src, half4* __restrict__ dst, int n4) {
    int i = blockIdx.x * blockDim.x + threadIdx.x;
    if (i < n4) {
        float4 v = src[i];
        half4 o;
        o[0] = (_Float16)v.x; o[1] = (_Float16)v.y;
        o[2] = (_Float16)v.z; o[3] = (_Float16)v.w;
        dst[i] = o;
    }
}

// ---------------- encoder layers 1,2: leaky(in @ W^T + b) ----------------
__global__ void enc12(const float* __restrict__ in, const float* __restrict__ W,
                      const float* __restrict__ bias, float* __restrict__ outb, int infeat) {
    int r = blockIdx.x, j = threadIdx.x;
    const float* row = in + (size_t)r * infeat;
    const float* w   = W  + (size_t)j * infeat;
    float s = bias[j];
    for (int k = 0; k < infeat; ++k) s += row[k] * w[k];
    outb[(size_t)r * blockDim.x + j] = (s >= 0.f) ? s : 0.01f * s;
}

// ---------------- encoder layer 3: h0 = h2 @ W3^T + b3 ----------------
__global__ void enc3(const float* __restrict__ h2, const float* __restrict__ W3,
                     const float* __restrict__ b3, float* __restrict__ hprev32,
                     _Float16* __restrict__ h0f16) {
    __shared__ float s[LAT_];
    int r = blockIdx.x;
    if (threadIdx.x < LAT_) s[threadIdx.x] = h2[(size_t)r * LAT_ + threadIdx.x];
    __syncthreads();
    for (int j = threadIdx.x; j < H_; j += 256) {
        const float* w = W3 + (size_t)j * LAT_;
        float acc = b3[j];
        #pragma unroll 8
        for (int k = 0; k < LAT_; ++k) acc += s[k] * w[k];
        hprev32[(size_t)r * H_ + j] = acc;
        h0f16[(size_t)r * H_ + j]   = (_Float16)acc;
    }
}

// ---------------- persistent GRU: all 168 steps in one launch ----------------
// 256 WGs: pi=blk&15 -> rows [16pi,+16); qi=blk>>4 -> units [64qi,+64). 4 waves;
// wave w owns units [64qi+16w,+16). Whh r,z gates resident in VGPRs (256); n gate
// streamed from L2 each step. h exchanged via agent-scope 8B atomics (sc-coherent,
// no cache flushes); per-pi 16-WG monotonic-counter barrier.
__global__ __launch_bounds__(256, 1) void gru_persistent(
    _Float16* __restrict__ hb0, _Float16* __restrict__ hb1,
    const float* __restrict__ hprev32, const _Float16* __restrict__ whh16,
    const _Float16* __restrict__ wih16, const _Float16* __restrict__ x16,
    const float* __restrict__ bih, const float* __restrict__ bhh,
    const float* __restrict__ Wo, float* __restrict__ partials,
    unsigned* __restrict__ bar)
{
    __shared__ __align__(16) _Float16 Ash[16 * 1032];   // 16 h-rows x 1024k (+8 pad)
    __shared__ __align__(16) _Float16 Wsh[192 * 72];    // Wih slice
    __shared__ __align__(16) _Float16 Hsh[1024];        // h-out transpose

    const int tid  = threadIdx.x;
    const int w    = tid >> 6;
    const int lane = tid & 63;
    const int m16  = lane & 15;
    const int quad = lane >> 4;
    const int pi   = blockIdx.x & 15;
    const int qi   = blockIdx.x >> 4;
    const int pi16 = pi << 4;
    const int u    = (qi << 6) + (w << 4) + m16;

    // Wih slice -> LDS (once)
    for (int idx = tid; idx < 1536; idx += 256) {
        int rowl = idx >> 3, ch = idx & 7;
        int g = rowl >> 6, ru = rowl & 63;
        *(uint4*)(&Wsh[rowl * 72 + (ch << 3)]) =
            *(const uint4*)(wih16 + (size_t)(((g << 10) + (qi << 6) + ru) << 6) + (ch << 3));
    }

    // Resident Whh fragments: r,z gates only (64 frags = 256 VGPR)
    half8 br[32], bz[32];
    {
        const _Float16* p0 = whh16 + ((size_t)u << 10) + (quad << 3);
        const _Float16* p1 = whh16 + ((size_t)(H_ + u) << 10) + (quad << 3);
        #pragma unroll
        for (int c = 0; c < 32; ++c) br[c] = *(const half8*)(p0 + (c << 5));
        #pragma unroll
        for (int c = 0; c < 32; ++c) bz[c] = *(const half8*)(p1 + (c << 5));
    }
    const _Float16* bnp = whh16 + ((size_t)(2 * H_ + u) << 10) + (quad << 3);

    const float b_r  = bih[u]          + bhh[u];
    const float b_z  = bih[H_ + u]     + bhh[H_ + u];
    const float b_in = bih[2 * H_ + u];
    const float b_hn = bhh[2 * H_ + u];
    const float wo_u = Wo[u];

    float hreg[4];
    #pragma unroll
    for (int i = 0; i < 4; ++i)
        hreg[i] = hprev32[((size_t)(pi16 + (quad << 2) + i) << 10) + u];

    __syncthreads();

    unsigned* cnt = bar + pi * 32;          // monotonic arrival counter
    unsigned* gen = bar + 512 + pi * 32;    // published generation

    for (int t = 0; t < T_; ++t) {
        const _Float16* hsrc = (t & 1) ? hb1 : hb0;
        _Float16*       hdst = (t & 1) ? hb0 : hb1;

        // stage h rows via agent-coherent 8B loads (bypass stale L1/L2)
        #pragma unroll
        for (int it = 0; it < 16; ++it) {
            int idx = tid + (it << 8);
            int row = idx >> 8, k4 = idx & 255;
            unsigned long long v = __hip_atomic_load(
                (const unsigned long long*)(hsrc + ((size_t)(pi16 + row) << 10) + (k4 << 2)),
                __ATOMIC_RELAXED, __HIP_MEMORY_SCOPE_AGENT);
            *(unsigned long long*)(&Ash[row * 1032 + (k4 << 2)]) = v;
        }
        __syncthreads();

        floatx4 acc_r  = {b_r,  b_r,  b_r,  b_r };
        floatx4 acc_z  = {b_z,  b_z,  b_z,  b_z };
        floatx4 acc_in = {b_in, b_in, b_in, b_in};
        floatx4 acc_hn = {b_hn, b_hn, b_hn, b_hn};

        // gi = x_t @ Wih^T  (K=64, Wih from LDS)
        #pragma unroll
        for (int c = 0; c < 2; ++c) {
            half8 ax = *(const half8*)(x16 + (((size_t)t << 8) + pi16 + m16) * WS_ + (c << 5) + (quad << 3));
            half8 p0 = *(const half8*)(&Wsh[((w << 4) + m16) * 72        + (c << 5) + (quad << 3)]);
            half8 p1 = *(const half8*)(&Wsh[(64 + (w << 4) + m16) * 72   + (c << 5) + (quad << 3)]);
            half8 p2 = *(const half8*)(&Wsh[(128 + (w << 4) + m16) * 72  + (c << 5) + (quad << 3)]);
            acc_r  = __builtin_amdgcn_mfma_f32_16x16x32_f16(ax, p0, acc_r,  0, 0, 0);
            acc_z  = __builtin_amdgcn_mfma_f32_16x16x32_f16(ax, p1, acc_z,  0, 0, 0);
            acc_in = __builtin_amdgcn_mfma_f32_16x16x32_f16(ax, p2, acc_in, 0, 0, 0);
        }

        // gh: r,z from resident VGPRs; n streamed from global (L2-warm), prefetch depth 8
        #pragma unroll
        for (int blk = 0; blk < 4; ++blk) {
            half8 bn[8];
            #pragma unroll
            for (int j = 0; j < 8; ++j)
                bn[j] = *(const half8*)(bnp + (((blk << 3) + j) << 5));
            #pragma unroll
            for (int j = 0; j < 8; ++j) {
                const int c = (blk << 3) + j;
                half8 a = *(const half8*)(&Ash[m16 * 1032 + (c << 5) + (quad << 3)]);
                acc_r  = __builtin_amdgcn_mfma_f32_16x16x32_f16(a, br[c], acc_r,  0, 0, 0);
                acc_z  = __builtin_amdgcn_mfma_f32_16x16x32_f16(a, bz[c], acc_z,  0, 0, 0);
                acc_hn = __builtin_amdgcn_mfma_f32_16x16x32_f16(a, bn[j], acc_hn, 0, 0, 0);
            }
        }

        // GRU nonlinearity; h stays in registers
        float pv[4];
        #pragma unroll
        for (int i = 0; i < 4; ++i) {
            float rg = 1.f / (1.f + __expf(-acc_r[i]));
            float zg = 1.f / (1.f + __expf(-acc_z[i]));
            float ng = tanhf(acc_in[i] + rg * acc_hn[i]);
            float hn2 = (1.f - zg) * ng + zg * hreg[i];
            hreg[i] = hn2;
            pv[i] = hn2 * wo_u;
            Hsh[((quad << 2) + i) * 64 + (w << 4) + m16] = (_Float16)hn2;
        }
        #pragma unroll
        for (int m = 1; m < 16; m <<= 1) {
            #pragma unroll
            for (int i = 0; i < 4; ++i) pv[i] += __shfl_xor(pv[i], m);
        }
        if (m16 == 0) {
            #pragma unroll
            for (int i = 0; i < 4; ++i)
                partials[((size_t)t * B_ + pi16 + (quad << 2) + i) * 64 + (qi << 2) + w] = pv[i];
        }
        __syncthreads();

        // publish h16 via agent-coherent 8B store (write-through to coherence point)
        {
            unsigned long long hv = *(const unsigned long long*)(&Hsh[tid << 2]);
            __hip_atomic_store(
                (unsigned long long*)(hdst + ((size_t)(pi16 + (tid >> 4)) << 10) + (qi << 6) + ((tid & 15) << 2)),
                hv, __ATOMIC_RELAXED, __HIP_MEMORY_SCOPE_AGENT);
        }

        if (t < T_ - 1) {
            asm volatile("s_waitcnt vmcnt(0)" ::: "memory");  // h stores complete at L3
            __syncthreads();                                   // all 4 waves drained
            if (tid == 0) {
                unsigned old = __hip_atomic_fetch_add(cnt, 1u, __ATOMIC_RELAXED, __HIP_MEMORY_SCOPE_AGENT);
                if (old == (unsigned)(16 * (t + 1) - 1)) {
                    __hip_atomic_store(gen, (unsigned)(t + 1), __ATOMIC_RELAXED, __HIP_MEMORY_SCOPE_AGENT);
                } else {
                    while (__hip_atomic_load(gen, __ATOMIC_RELAXED, __HIP_MEMORY_SCOPE_AGENT) < (unsigned)(t + 1))
                        __builtin_amdgcn_s_sleep(2);
                }
            }
            __syncthreads();
        }
    }
}

// ---------------- final: out[r,t] = sum_q partials[t,r,q] + bo ----------------
__global__ void out_reduce(const float* __restrict__ partials, const float* __restrict__ bo,
                           float* __restrict__ out) {
    int t = blockIdx.x, r = threadIdx.x;
    const float* p = partials + ((size_t)t * B_ + r) * 64;
    float s = 0.f;
    #pragma unroll
    for (int i = 0; i < 64; ++i) s += p[i];
    out[(size_t)r * T_ + t] = s + bo[0];
}

extern "C" void kernel_launch(void* const* d_in, const int* in_sizes, int n_in,
                              void* d_out, int out_size, void* d_ws, size_t ws_size,
                              hipStream_t stream) {
    const float* lag  = (const float*)d_in[0];
    const float* curr = (const float*)d_in[1];
    const float* W1   = (const float*)d_in[2];
    const float* b1   = (const float*)d_in[3];
    const float* W2   = (const float*)d_in[4];
    const float* b2   = (const float*)d_in[5];
    const float* W3   = (const float*)d_in[6];
    const float* b3   = (const float*)d_in[7];
    const float* Wih  = (const float*)d_in[8];
    const float* Whh  = (const float*)d_in[9];
    const float* bih  = (const float*)d_in[10];
    const float* bhh  = (const float*)d_in[11];
    const float* Wo   = (const float*)d_in[12];
    const float* bo   = (const float*)d_in[13];
    float* out = (float*)d_out;

    char* ws = (char*)d_ws;
    size_t off = 0;
    auto alloc = [&](size_t bytes) -> void* {
        void* p = ws + off;
        off += (bytes + 255) & ~(size_t)255;
        return p;
    };
    _Float16* whh16 = (_Float16*)alloc((size_t)3 * H_ * H_ * 2);
    _Float16* wih16 = (_Float16*)alloc((size_t)3 * H_ * WS_ * 2);
    _Float16* x16   = (_Float16*)alloc((size_t)T_ * B_ * WS_ * 2);
    _Float16* hb0   = (_Float16*)alloc((size_t)B_ * H_ * 2);
    _Float16* hb1   = (_Float16*)alloc((size_t)B_ * H_ * 2);
    float* hprev32  = (float*)alloc((size_t)B_ * H_ * 4);
    float* h1       = (float*)alloc((size_t)B_ * 64 * 4);
    float* h2       = (float*)alloc((size_t)B_ * LAT_ * 4);
    float* partials = (float*)alloc((size_t)T_ * B_ * 64 * 4);
    unsigned* bar   = (unsigned*)alloc(1024 * 4);

    hipMemsetAsync(bar, 0, 1024 * 4, stream);

    int n4;
    n4 = 3 * H_ * H_ / 4;
    cvt_f32_f16_v4<<<(n4 + 255) / 256, 256, 0, stream>>>((const float4*)Whh, (half4*)whh16, n4);
    n4 = 3 * H_ * WS_ / 4;
    cvt_f32_f16_v4<<<(n4 + 255) / 256, 256, 0, stream>>>((const float4*)Wih, (half4*)wih16, n4);
    n4 = T_ * B_ * WS_ / 4;
    cvt_f32_f16_v4<<<(n4 + 255) / 256, 256, 0, stream>>>((const float4*)curr, (half4*)x16, n4);

    enc12<<<B_, 64, 0, stream>>>(lag, W1, b1, h1, LAG_);
    enc12<<<B_, LAT_, 0, stream>>>(h1, W2, b2, h2, 64);
    enc3<<<B_, 256, 0, stream>>>(h2, W3, b3, hprev32, hb0);

    gru_persistent<<<dim3(256), dim3(256), 0, stream>>>(
        hb0, hb1, hprev32, whh16, wih16, x16, bih, bhh, Wo, partials, bar);

    out_reduce<<<T_, B_, 0, stream>>>(partials, bo, out);
}